// Round 2
// baseline (931.030 us; speedup 1.0000x reference)
//
#include <hip/hip_runtime.h>
#include <math.h>

#define BB 8
#define E  128
#define OO 256
#define HH 112
#define WW 112
#define HWP (HH*WW)   // 12544

// One fused kernel: cosine-sim 3x3 conv.
//   sim[b,o,h,w] = (sum_d w_raw[o,d] * patch[b,h,w,d]) / (||w_raw[o]|| * ||patch||)
// Both norms are deferred to the epilogue as scales, so no workspace is needed.
// Tile: 128 o x 64 w at fixed (b,h). 256 threads, each 8o x 4w.
// K (=1152) processed in 16 chunks of 8 channels (72 d per chunk).

__global__ __launch_bounds__(256)
void fused_cossim_kernel(const float* __restrict__ x, const float* __restrict__ wgt,
                         float* __restrict__ out) {
    int h  = blockIdx.x;            // 0..111
    int wt = blockIdx.y;            // 0..1
    int bz = blockIdx.z;            // b*2 + ot
    int b  = bz >> 1, ot = bz & 1;
    int w0 = wt * 64;
    int o0 = ot * 128;
    int t  = threadIdx.x;
    int wq = t & 15;                // w sub-lane: out pixels w0 + wq + 16j
    int og = t >> 4;                // o group: o0 + og*8 .. +7

    __shared__ float xs[8][3][66];     // chans ch0..+7, rows h-1..h+1, cols w0-1..w0+64
    __shared__ float wsT[72][128];     // raw weight slice, [d_local][o_local]
    __shared__ float ssqAcc[3][66];    // per-pixel channel sum-of-squares (accum over chunks)
    __shared__ float wSsq[128];        // per-o weight row sum-of-squares

    if (t < 198) ssqAcc[t / 66][t % 66] = 0.f;
    if (t < 128) wSsq[t] = 0.f;
    // (first __syncthreads below covers these inits)

    float acc[8][4];
    #pragma unroll
    for (int i = 0; i < 8; ++i)
        #pragma unroll
        for (int j = 0; j < 4; ++j) acc[i][j] = 0.f;

    const float* xb = x + (size_t)b * E * HWP;

    for (int ch0 = 0; ch0 < E; ch0 += 8) {
        // ---- stage x tile: 8*3*66 = 1584 floats
        for (int i = t; i < 8*3*66; i += 256) {
            int cc  = i / 198;
            int rem = i - cc * 198;
            int r   = rem / 66;
            int col = rem - r * 66;
            int gh = h - 1 + r;
            int gw = w0 - 1 + col;
            float v = 0.f;
            if ((unsigned)gh < HH && (unsigned)gw < WW)
                v = xb[(ch0 + cc) * HWP + gh * WW + gw];
            xs[cc][r][col] = v;
        }
        // ---- stage raw weight slice: 72 d x 128 o, read o-major rows as float4
        {
            int ol = t >> 1;                 // 0..127
            int qb = (t & 1) * 9;            // this thread: float4s qb..qb+8 of the 18
            const float* wrow = wgt + (size_t)(o0 + ol) * 1152 + ch0 * 9 + qb * 4;
            #pragma unroll
            for (int q = 0; q < 9; ++q) {
                float4 v = *(const float4*)(wrow + q * 4);
                int dl = (qb + q) * 4;
                wsT[dl + 0][ol] = v.x;
                wsT[dl + 1][ol] = v.y;
                wsT[dl + 2][ol] = v.z;
                wsT[dl + 3][ol] = v.w;
            }
        }
        __syncthreads();

        // ---- accumulate per-pixel channel sumsq (one owner thread per pixel)
        if (t < 198) {
            int r = t / 66, col = t % 66;
            float s = ssqAcc[r][col];
            #pragma unroll
            for (int cc = 0; cc < 8; ++cc) {
                float v = xs[cc][r][col];
                s = fmaf(v, v, s);
            }
            ssqAcc[r][col] = s;
        }
        // ---- accumulate per-o weight row sumsq (one owner thread per o)
        if (t < 128) {
            float s = wSsq[t];
            #pragma unroll
            for (int dl = 0; dl < 72; ++dl) {
                float v = wsT[dl][t];
                s = fmaf(v, v, s);
            }
            wSsq[t] = s;
        }

        // ---- main FMA: 72 d-elems x 8 o x 4 w per thread
        #pragma unroll
        for (int cc = 0; cc < 8; ++cc) {
            #pragma unroll
            for (int kh = 0; kh < 3; ++kh) {
                #pragma unroll
                for (int kw = 0; kw < 3; ++kw) {
                    int dl = cc * 9 + kh * 3 + kw;
                    const float4 wv0 = *(const float4*)&wsT[dl][og * 8];
                    const float4 wv1 = *(const float4*)&wsT[dl][og * 8 + 4];
                    #pragma unroll
                    for (int j = 0; j < 4; ++j) {
                        float xv = xs[cc][kh][wq + 16 * j + kw];
                        acc[0][j] = fmaf(wv0.x, xv, acc[0][j]);
                        acc[1][j] = fmaf(wv0.y, xv, acc[1][j]);
                        acc[2][j] = fmaf(wv0.z, xv, acc[2][j]);
                        acc[3][j] = fmaf(wv0.w, xv, acc[3][j]);
                        acc[4][j] = fmaf(wv1.x, xv, acc[4][j]);
                        acc[5][j] = fmaf(wv1.y, xv, acc[5][j]);
                        acc[6][j] = fmaf(wv1.z, xv, acc[6][j]);
                        acc[7][j] = fmaf(wv1.w, xv, acc[7][j]);
                    }
                }
            }
        }
        __syncthreads();   // protects xs/wsT for next chunk; also orders ssqAcc/wSsq
    }

    // ---- epilogue: scale by 1/||w_row|| and 1/||patch||
    float winv[8];
    #pragma unroll
    for (int i = 0; i < 8; ++i)
        winv[i] = 1.0f / fmaxf(sqrtf(wSsq[og * 8 + i]), 1e-12f);

    #pragma unroll
    for (int j = 0; j < 4; ++j) {
        int k = wq + 16 * j;          // xs-col of out pixel minus 1
        int wpix = w0 + k;
        if (wpix < WW) {
            float S = 0.f;
            #pragma unroll
            for (int r = 0; r < 3; ++r)
                S += ssqAcc[r][k] + ssqAcc[r][k + 1] + ssqAcc[r][k + 2];
            float pinv = 1.0f / fmaxf(sqrtf(S), 1e-12f);
            #pragma unroll
            for (int i = 0; i < 8; ++i) {
                out[((size_t)(b * OO + o0 + og * 8 + i)) * HWP + h * WW + wpix]
                    = acc[i][j] * winv[i] * pinv;
            }
        }
    }
}

extern "C" void kernel_launch(void* const* d_in, const int* in_sizes, int n_in,
                              void* d_out, int out_size, void* d_ws, size_t ws_size,
                              hipStream_t stream) {
    const float* x   = (const float*)d_in[0];
    const float* wgt = (const float*)d_in[1];
    float* out = (float*)d_out;
    (void)d_ws; (void)ws_size;   // no workspace: all state is per-block LDS

    fused_cossim_kernel<<<dim3(HH, 2, BB * 2), 256, 0, stream>>>(x, wgt, out);
}

// Round 3
// 164.284 us; speedup vs baseline: 5.6672x; 5.6672x over previous
//
#include <hip/hip_runtime.h>
#include <math.h>

#define BB 8
#define E  128
#define OO 256
#define HH 112
#define WW 112
#define HWP (HH*WW)   // 12544

typedef _Float16 f16;
typedef _Float16 half8 __attribute__((ext_vector_type(8)));
typedef float f32x4 __attribute__((ext_vector_type(4)));

// Fused cosine-sim 3x3 conv, f16 MFMA core, fp32 norms, zero workspace.
// Block: 64 o x 2 h x 128 w. 4 waves; wave = 64o x 64px (m4 x n4 frags of 16x16).
// K = 1152 processed as 4 chunks of 32 channels x 9 taps (k-step 32 = chunk).

__global__ __launch_bounds__(256, 2)
void cossim_mfma(const float* __restrict__ x, const float* __restrict__ wgt,
                 float* __restrict__ out) {
    int hp = blockIdx.x;        // 0..55   -> h0 = hp*2
    int oy = blockIdx.y;        // 0..3    -> o0 = oy*64
    int b  = blockIdx.z;        // 0..7
    int h0 = hp * 2;
    int o0 = oy * 64;
    int t    = threadIdx.x;
    int lane = t & 63;
    int wv   = t >> 6;          // wave id 0..3 -> w-base wv*32

    __shared__ f16   ws[9][64][32];     // [tap][o_local][c]  36864 B
    __shared__ f16   xs[4][130][32];    // [row][col][c]      33280 B (col = gw+1)
    __shared__ float ssqAcc[4][130];    // per-pixel channel sumsq (fp32 x)
    __shared__ float wSsq[64];
    __shared__ float pinvL[2][128];
    __shared__ float winv[64];

    // zero norm accumulators
    for (int i = t; i < 4*130 + 64; i += 256) {
        if (i < 4*130) ((float*)ssqAcc)[i] = 0.f;
        else wSsq[i - 4*130] = 0.f;
    }
    __syncthreads();

    f32x4 zero4 = {0.f, 0.f, 0.f, 0.f};
    f32x4 acc[4][4];
    #pragma unroll
    for (int mi = 0; mi < 4; ++mi)
        #pragma unroll
        for (int ni = 0; ni < 4; ++ni) acc[mi][ni] = zero4;

    const int lr = lane & 15;   // fragment row/col index
    const int ls = lane >> 4;   // k-group 0..3

    for (int ch0 = 0; ch0 < E; ch0 += 32) {
        // ---------- stage weights: thread (o = t>>2, q = t&3) reads 72 contiguous
        // floats w[o0+o][ch0*9 + q*72 ...], transposes (c,tap) in-register,
        // writes 9 x b128 to ws[tap][o][q*8..+7]. Lane-contiguous LDS writes.
        {
            int o = t >> 2, q = t & 3;
            const float* wrow = wgt + (size_t)(o0 + o) * 1152 + ch0 * 9 + q * 72;
            float v[72];
            float ss = 0.f;
            #pragma unroll
            for (int i = 0; i < 18; ++i) {
                float4 f = ((const float4*)wrow)[i];
                v[i*4+0] = f.x; v[i*4+1] = f.y; v[i*4+2] = f.z; v[i*4+3] = f.w;
                ss = fmaf(f.x, f.x, ss); ss = fmaf(f.y, f.y, ss);
                ss = fmaf(f.z, f.z, ss); ss = fmaf(f.w, f.w, ss);
            }
            #pragma unroll
            for (int tp = 0; tp < 9; ++tp) {
                half8 pk;
                #pragma unroll
                for (int cl = 0; cl < 8; ++cl) pk[cl] = (f16)v[cl*9 + tp];
                *(half8*)&ws[tp][o][q*8] = pk;
            }
            ss += __shfl_xor(ss, 1);
            ss += __shfl_xor(ss, 2);
            if (q == 0) wSsq[o] += ss;   // unique owner per o
        }

        // ---------- stage x: per wave-iter 16 cols x 4 c-octets; coalesced global
        // reads (16x64B lines), one conflict-free b128 LDS write per lane.
        {
            int colL = lane & 15, cq = lane >> 4;
            #pragma unroll 2
            for (int it = 0; it < 9; ++it) {
                int g = it * 4 + wv;          // 0..35
                int r = g / 9, colb = g % 9;
                int cs = colb * 16 + colL;    // col slot 0..143 (valid < 130)
                int gh = h0 - 1 + r;
                int gw = cs - 1;
                bool okc = (cs < 130);
                bool ok  = okc && ((unsigned)gh < HH) && ((unsigned)gw < WW);
                const float* xp = x + ((size_t)b * E + ch0 + cq * 8) * HWP + gh * WW + gw;
                float vv[8];
                float ss = 0.f;
                #pragma unroll
                for (int e = 0; e < 8; ++e) {
                    float v = ok ? xp[e * HWP] : 0.f;
                    vv[e] = v;
                    ss = fmaf(v, v, ss);
                }
                if (okc) {
                    half8 pk;
                    #pragma unroll
                    for (int e = 0; e < 8; ++e) pk[e] = (f16)vv[e];
                    *(half8*)&xs[r][cs][cq*8] = pk;
                }
                ss += __shfl_xor(ss, 16);
                ss += __shfl_xor(ss, 32);
                if (cq == 0 && okc) ssqAcc[r][cs] += ss;   // unique owner per (r,cs)
            }
        }
        __syncthreads();

        // ---------- MFMA: 9 taps x (4 A-frags + 4 B-frags + 16 mfma)
        #pragma unroll
        for (int tap = 0; tap < 9; ++tap) {
            int kh = tap / 3, kw = tap % 3;
            half8 A[4], Bf[4];
            #pragma unroll
            for (int mi = 0; mi < 4; ++mi)
                A[mi] = *(const half8*)&ws[tap][mi*16 + lr][ls*8];
            #pragma unroll
            for (int dh = 0; dh < 2; ++dh)
                #pragma unroll
                for (int wsg = 0; wsg < 2; ++wsg)
                    Bf[dh*2 + wsg] = *(const half8*)&xs[dh + kh][wv*32 + wsg*16 + lr + kw][ls*8];
            #pragma unroll
            for (int mi = 0; mi < 4; ++mi)
                #pragma unroll
                for (int ni = 0; ni < 4; ++ni)
                    acc[mi][ni] = __builtin_amdgcn_mfma_f32_16x16x32_f16(
                        A[mi], Bf[ni], acc[mi][ni], 0, 0, 0);
        }
        __syncthreads();
    }

    // ---------- epilogue: inverse norms, then scaled store
    if (t < 64) winv[t] = rsqrtf(fmaxf(wSsq[t], 1e-24f));
    {
        int dh = t >> 7, w = t & 127;   // all 256 threads
        float S = 0.f;
        #pragma unroll
        for (int r = 0; r < 3; ++r)
            #pragma unroll
            for (int c = 0; c < 3; ++c)
                S += ssqAcc[dh + r][w + c];
        pinvL[dh][w] = rsqrtf(fmaxf(S, 1e-24f));
    }
    __syncthreads();

    int lq = lane >> 4;
    #pragma unroll
    for (int ni = 0; ni < 4; ++ni) {
        int dh = ni >> 1, wsg = ni & 1;
        int w = wv * 32 + wsg * 16 + lr;
        if (w >= WW) continue;
        float pv = pinvL[dh][w];
        int h = h0 + dh;
        #pragma unroll
        for (int mi = 0; mi < 4; ++mi) {
            #pragma unroll
            for (int rg = 0; rg < 4; ++rg) {
                int row = lq * 4 + rg;
                float wv_s = winv[mi*16 + row];
                out[((size_t)(b * OO + o0 + mi*16 + row)) * HWP + h * WW + w]
                    = acc[mi][ni][rg] * wv_s * pv;
            }
        }
    }
}

extern "C" void kernel_launch(void* const* d_in, const int* in_sizes, int n_in,
                              void* d_out, int out_size, void* d_ws, size_t ws_size,
                              hipStream_t stream) {
    const float* x   = (const float*)d_in[0];
    const float* wgt = (const float*)d_in[1];
    float* out = (float*)d_out;
    (void)d_ws; (void)ws_size;

    cossim_mfma<<<dim3(56, 4, 8), 256, 0, stream>>>(x, wgt, out);
}

// Round 4
// 139.825 us; speedup vs baseline: 6.6586x; 1.1749x over previous
//
#include <hip/hip_runtime.h>
#include <math.h>

#define BB 8
#define E  128
#define OO 256
#define HH 112
#define WW 112
#define HWP (HH*WW)   // 12544

typedef _Float16 f16;
typedef _Float16 half8 __attribute__((ext_vector_type(8)));
typedef float f32x4 __attribute__((ext_vector_type(4)));

// LDS octet swizzle: logical octet q (8 f16) at logical column/row c lives at
// physical octet ((q + (c>>1)) & 3). Bank-floor-optimal for both the 16-row x
// 4-octet A reads and the 16-col-window B reads (2-way max = free per m136).
#define SWZ(q, c) ((((q) + ((c) >> 1)) & 3) * 8)

// ---------------- precompute: normalized f16 weights, layout [tap][o][ch]
__global__ __launch_bounds__(128)
void wnorm16_kernel(const float* __restrict__ wgt, f16* __restrict__ wn16) {
    int o = blockIdx.x;       // 0..255
    int c = threadIdx.x;      // 0..127 channel
    const float* row = wgt + (size_t)o * 1152 + c * 9;
    float v[9];
    float ss = 0.f;
    #pragma unroll
    for (int tp = 0; tp < 9; ++tp) { v[tp] = row[tp]; ss = fmaf(v[tp], v[tp], ss); }
    ss += __shfl_xor(ss, 1);  ss += __shfl_xor(ss, 2);
    ss += __shfl_xor(ss, 4);  ss += __shfl_xor(ss, 8);
    ss += __shfl_xor(ss, 16); ss += __shfl_xor(ss, 32);
    __shared__ float r2[2];
    if ((c & 63) == 0) r2[c >> 6] = ss;
    __syncthreads();
    float inv = rsqrtf(fmaxf(r2[0] + r2[1], 1e-24f));
    #pragma unroll
    for (int tp = 0; tp < 9; ++tp)
        wn16[((size_t)tp * OO + o) * E + c] = (f16)(v[tp] * inv);
}

// ---------------- main fused kernel
// Block: 64 o x 2 h x 128 w. 4 waves; wave = 64o x 64px (m4 x n4 frags 16x16x32).
// FAST=1: weights from pre-normalized f16 wn16 (d_ws). FAST=0: in-block transpose.
template<int FAST>
__global__ __launch_bounds__(256, 2)
void cossim_mfma(const float* __restrict__ x, const float* __restrict__ wgt,
                 const f16* __restrict__ wn16, float* __restrict__ out) {
    int hp = blockIdx.x;        // 0..55
    int oy = blockIdx.y;        // 0..3
    int b  = blockIdx.z;        // 0..7
    int h0 = hp * 2;
    int o0 = oy * 64;
    int t    = threadIdx.x;
    int lane = t & 63;
    int wv   = t >> 6;

    __shared__ f16   ws[9][64][32];
    __shared__ f16   xs[4][130][32];
    __shared__ float ssqAcc[4][130];
    __shared__ float wSsq[64];
    __shared__ float pinvL[2][128];
    __shared__ float winv[64];

    for (int i = t; i < 4*130 + 64; i += 256) {
        if (i < 4*130) ((float*)ssqAcc)[i] = 0.f;
        else wSsq[i - 4*130] = 0.f;
    }
    __syncthreads();

    f32x4 zero4 = {0.f, 0.f, 0.f, 0.f};
    f32x4 acc[4][4];
    #pragma unroll
    for (int mi = 0; mi < 4; ++mi)
        #pragma unroll
        for (int ni = 0; ni < 4; ++ni) acc[mi][ni] = zero4;

    const int lr = lane & 15;
    const int ls = lane >> 4;

    for (int ch0 = 0; ch0 < E; ch0 += 32) {
        // ---------- stage weights
        if (FAST) {
            int o = t >> 2, q = t & 3;
            #pragma unroll
            for (int r = 0; r < 9; ++r) {
                half8 v = *(const half8*)(wn16 + ((size_t)(r * OO + o0 + o)) * E + ch0 + q * 8);
                *(half8*)&ws[r][o][SWZ(q, o)] = v;
            }
        } else {
            int o = t >> 2, q = t & 3;
            const float* wrow = wgt + (size_t)(o0 + o) * 1152 + ch0 * 9 + q * 72;
            float v[72];
            float ss = 0.f;
            #pragma unroll
            for (int i = 0; i < 18; ++i) {
                float4 f = ((const float4*)wrow)[i];
                v[i*4+0] = f.x; v[i*4+1] = f.y; v[i*4+2] = f.z; v[i*4+3] = f.w;
                ss = fmaf(f.x, f.x, ss); ss = fmaf(f.y, f.y, ss);
                ss = fmaf(f.z, f.z, ss); ss = fmaf(f.w, f.w, ss);
            }
            #pragma unroll
            for (int tp = 0; tp < 9; ++tp) {
                half8 pk;
                #pragma unroll
                for (int cl = 0; cl < 8; ++cl) pk[cl] = (f16)v[cl*9 + tp];
                *(half8*)&ws[tp][o][SWZ(q, o)] = pk;
            }
            ss += __shfl_xor(ss, 1);
            ss += __shfl_xor(ss, 2);
            if (q == 0) wSsq[o] += ss;
        }

        // ---------- stage x (f32 loads, ssq accumulation, swizzled f16 LDS store)
        {
            int colL = lane & 15, cq = lane >> 4;
            #pragma unroll 2
            for (int it = 0; it < 9; ++it) {
                int g = it * 4 + wv;          // 0..35
                int r = g / 9, colb = g % 9;
                int cs = colb * 16 + colL;    // 0..143 (valid < 130)
                int gh = h0 - 1 + r;
                int gw = cs - 1;
                bool okc = (cs < 130);
                bool ok  = okc && ((unsigned)gh < HH) && ((unsigned)gw < WW);
                const float* xp = x + ((size_t)b * E + ch0 + cq * 8) * HWP + gh * WW + gw;
                float vv[8];
                float ss = 0.f;
                #pragma unroll
                for (int e = 0; e < 8; ++e) {
                    float v = ok ? xp[e * HWP] : 0.f;
                    vv[e] = v;
                    ss = fmaf(v, v, ss);
                }
                if (okc) {
                    half8 pk;
                    #pragma unroll
                    for (int e = 0; e < 8; ++e) pk[e] = (f16)vv[e];
                    *(half8*)&xs[r][cs][SWZ(cq, cs)] = pk;
                }
                ss += __shfl_xor(ss, 16);
                ss += __shfl_xor(ss, 32);
                if (cq == 0 && okc) ssqAcc[r][cs] += ss;
            }
        }
        __syncthreads();

        // ---------- MFMA
        __builtin_amdgcn_s_setprio(1);
        #pragma unroll
        for (int tap = 0; tap < 9; ++tap) {
            int kh = tap / 3, kw = tap % 3;
            half8 A[4], Bf[4];
            #pragma unroll
            for (int mi = 0; mi < 4; ++mi) {
                int row = mi * 16 + lr;
                A[mi] = *(const half8*)&ws[tap][row][SWZ(ls, row)];
            }
            #pragma unroll
            for (int dh = 0; dh < 2; ++dh)
                #pragma unroll
                for (int wsg = 0; wsg < 2; ++wsg) {
                    int col = wv * 32 + wsg * 16 + lr + kw;
                    Bf[dh*2 + wsg] = *(const half8*)&xs[dh + kh][col][SWZ(ls, col)];
                }
            #pragma unroll
            for (int mi = 0; mi < 4; ++mi)
                #pragma unroll
                for (int ni = 0; ni < 4; ++ni)
                    acc[mi][ni] = __builtin_amdgcn_mfma_f32_16x16x32_f16(
                        A[mi], Bf[ni], acc[mi][ni], 0, 0, 0);
        }
        __builtin_amdgcn_s_setprio(0);
        __syncthreads();
    }

    // ---------- epilogue
    if (!FAST && t < 64) winv[t] = rsqrtf(fmaxf(wSsq[t], 1e-24f));
    {
        int dh = t >> 7, w = t & 127;
        float S = 0.f;
        #pragma unroll
        for (int r = 0; r < 3; ++r)
            #pragma unroll
            for (int c = 0; c < 3; ++c)
                S += ssqAcc[dh + r][w + c];
        pinvL[dh][w] = rsqrtf(fmaxf(S, 1e-24f));
    }
    __syncthreads();

    int lq = lane >> 4;
    #pragma unroll
    for (int ni = 0; ni < 4; ++ni) {
        int dh = ni >> 1, wsg = ni & 1;
        int w = wv * 32 + wsg * 16 + lr;
        if (w >= WW) continue;
        float pv = pinvL[dh][w];
        int h = h0 + dh;
        #pragma unroll
        for (int mi = 0; mi < 4; ++mi) {
            #pragma unroll
            for (int rg = 0; rg < 4; ++rg) {
                int row = lq * 4 + rg;
                float s = acc[mi][ni][rg] * pv;
                if (!FAST) s *= winv[mi*16 + row];
                out[((size_t)(b * OO + o0 + mi*16 + row)) * HWP + h * WW + w] = s;
            }
        }
    }
}

extern "C" void kernel_launch(void* const* d_in, const int* in_sizes, int n_in,
                              void* d_out, int out_size, void* d_ws, size_t ws_size,
                              hipStream_t stream) {
    const float* x   = (const float*)d_in[0];
    const float* wgt = (const float*)d_in[1];
    float* out = (float*)d_out;

    const size_t need = (size_t)9 * OO * E * sizeof(f16);   // 589824 B
    if (ws_size >= need && d_ws != nullptr) {
        f16* wn16 = (f16*)d_ws;
        wnorm16_kernel<<<OO, 128, 0, stream>>>(wgt, wn16);
        cossim_mfma<1><<<dim3(56, 4, 8), 256, 0, stream>>>(x, wgt, wn16, out);
    } else {
        cossim_mfma<0><<<dim3(56, 4, 8), 256, 0, stream>>>(x, wgt, nullptr, out);
    }
}